// Round 2
// baseline (445.468 us; speedup 1.0000x reference)
//
#include <hip/hip_runtime.h>
#include <hip/hip_bf16.h>

// GroupLinearEncoder: N=64, L0=257,C0=1024, L1=197,C1=768, H=1024, P=2048, G=8, K=39548
// v3 pipeline:
//   pre-pass: x0,x1,w2_0,w2_1 -> bf16 copies in ws
//   gemm_fused<L>: m97-structure bf16 GEMM (global_load_lds w=16, BK=64, XOR-swizzled LDS)
//     with fused reduce epilogue: z[n,k] += sum_l M[n*L+l,k]*w1[k,l] via atomics
//   bn_latent -> lat[n][h] row-major; s_combine float4-vectorized -> sb (bf16, L2-resident)
//   gemm_embed: LDS-free direct-stream MFMA; B-frags from global f32 loads of embed_w,
//     A-frags from bf16 sb; grid (309 x 2 K-halves) -> 2 partial slabs; reduce_out sums + 2*eb

typedef __attribute__((ext_vector_type(4))) float f32x4;
typedef __attribute__((ext_vector_type(8))) short bf16x8;

__device__ __forceinline__ short f2bf(float v) {
  __hip_bfloat16 h = __float2bfloat16(v);
  union { __hip_bfloat16 b; short s; } u; u.b = h; return u.s;
}

__device__ __forceinline__ void gload16(const short* g, short* l) {
  __builtin_amdgcn_global_load_lds(
      (const __attribute__((address_space(1))) void*)g,
      (__attribute__((address_space(3))) void*)l, 16, 0, 0);
}

// f32 -> bf16, 8 elems/thread
__global__ __launch_bounds__(256) void to_bf16(const float* __restrict__ in,
                                               short* __restrict__ out, int n8)
{
  int i = blockIdx.x * 256 + threadIdx.x;
  if (i >= n8) return;
  const float4* p = reinterpret_cast<const float4*>(in) + 2 * (size_t)i;
  float4 a = p[0], b = p[1];
  bf16x8 o;
  o[0] = f2bf(a.x); o[1] = f2bf(a.y); o[2] = f2bf(a.z); o[3] = f2bf(a.w);
  o[4] = f2bf(b.x); o[5] = f2bf(b.y); o[6] = f2bf(b.z); o[7] = f2bf(b.w);
  *reinterpret_cast<bf16x8*>(out + 8 * (size_t)i) = o;
}

// C = A(bf16, Mpad x K) @ B(bf16, 1024 x K)^T, fused with
// z[n,col] += sum_l C[n*L+l, col] * w1[col*L + l]   (atomics; z pre-zeroed)
// 128x128 tile, BK=64, 4 waves (2x2), FM=FN=4.
template<int L>
__global__ __launch_bounds__(256) void gemm_fused(
    const short* __restrict__ Ab, const short* __restrict__ Bb,
    const float* __restrict__ w1, float* __restrict__ z,
    int M, int K)
{
  __shared__ short As[128 * 64];
  __shared__ short Bs[128 * 64];
  const int tid  = threadIdx.x;
  const int lane = tid & 63;
  const int wave = tid >> 6;
  const int wm = wave >> 1, wn = wave & 1;     // 2x2 wave grid, 64x64 per wave
  const int tile_m = blockIdx.y * 128;
  const int tile_n = blockIdx.x * 128;
  const int rl = lane & 15;
  const int lh = lane >> 4;

  f32x4 acc[4][4] = {};

  for (int k0 = 0; k0 < K; k0 += 64) {
    __syncthreads();
#pragma unroll
    for (int c = 0; c < 4; ++c) {
      int o = (c * 256 + tid) * 16;            // byte offset in LDS (linear dest)
      int r = o >> 7;
      int sc = ((o >> 4) & 7) ^ (r & 7);
      gload16(Ab + (size_t)(tile_m + r) * K + k0 + sc * 8,
              (short*)((char*)As + o));
    }
#pragma unroll
    for (int c = 0; c < 4; ++c) {
      int o = (c * 256 + tid) * 16;
      int r = o >> 7;
      int sc = ((o >> 4) & 7) ^ (r & 7);
      gload16(Bb + (size_t)(tile_n + r) * K + k0 + sc * 8,
              (short*)((char*)Bs + o));
    }
    __syncthreads();

#pragma unroll
    for (int ks = 0; ks < 2; ++ks) {
      bf16x8 af[4], bfr[4];
#pragma unroll
      for (int mi = 0; mi < 4; ++mi) {
        int r = wm * 64 + mi * 16 + rl;
        int j = (ks * 4 + lh) ^ (r & 7);
        af[mi] = *reinterpret_cast<const bf16x8*>((const char*)As + r * 128 + j * 16);
      }
#pragma unroll
      for (int ni = 0; ni < 4; ++ni) {
        int r = wn * 64 + ni * 16 + rl;
        int j = (ks * 4 + lh) ^ (r & 7);
        bfr[ni] = *reinterpret_cast<const bf16x8*>((const char*)Bs + r * 128 + j * 16);
      }
#pragma unroll
      for (int mi = 0; mi < 4; ++mi)
#pragma unroll
        for (int ni = 0; ni < 4; ++ni)
          acc[mi][ni] = __builtin_amdgcn_mfma_f32_16x16x32_bf16(af[mi], bfr[ni], acc[mi][ni], 0, 0, 0);
    }
  }

  // fused reduce_z epilogue. C/D layout: col=lane&15, row=(lane>>4)*4+j (m89).
#pragma unroll
  for (int ni = 0; ni < 4; ++ni) {
    int col = tile_n + wn * 64 + ni * 16 + rl;
    float zac = 0.f;
    int curn = -1;
#pragma unroll
    for (int mi = 0; mi < 4; ++mi) {
#pragma unroll
      for (int j = 0; j < 4; ++j) {
        int row = tile_m + wm * 64 + mi * 16 + lh * 4 + j;
        if (row < M) {
          int n = row / L, l = row - n * L;
          float v = acc[mi][ni][j] * w1[(size_t)col * L + l];
          if (n != curn) {
            if (curn >= 0) atomicAdd(z + curn * 1024 + col, zac);
            curn = n; zac = 0.f;
          }
          zac += v;
        }
      }
    }
    if (curn >= 0) atomicAdd(z + curn * 1024 + col, zac);
  }
}

// BN(z0), BN(z1) (biased stats over n=64), latent=0.5*(...+...), stored lat[n*1024+k]
__global__ void bn_latent(const float* __restrict__ z0, const float* __restrict__ z1,
                          const float* __restrict__ g0, const float* __restrict__ b0,
                          const float* __restrict__ g1, const float* __restrict__ b1,
                          float* __restrict__ lat)
{
  int k = blockIdx.x * blockDim.x + threadIdx.x;
  if (k >= 1024) return;
  float s0 = 0.f, q0 = 0.f, s1 = 0.f, q1 = 0.f;
  for (int n = 0; n < 64; ++n) {
    float v = z0[n * 1024 + k]; s0 += v; q0 += v * v;
    float w = z1[n * 1024 + k]; s1 += w; q1 += w * w;
  }
  float mu0 = s0 * (1.f / 64.f), var0 = q0 * (1.f / 64.f) - mu0 * mu0;
  float mu1 = s1 * (1.f / 64.f), var1 = q1 * (1.f / 64.f) - mu1 * mu1;
  float sc0 = g0[k] * rsqrtf(var0 + 1e-5f);
  float sc1 = g1[k] * rsqrtf(var1 + 1e-5f);
  float be0 = b0[k], be1 = b1[k];
  for (int n = 0; n < 64; ++n) {
    float v = sc0 * (z0[n * 1024 + k] - mu0) + be0
            + sc1 * (z1[n * 1024 + k] - mu1) + be1;
    lat[n * 1024 + k] = 0.5f * v;   // coalesced across k
  }
}

// sb[n,p] = bf16( lat[n,:]·(sw[p,:]+fw[g_n*2048+p,:]) + fb[g_n*2048+p] )
__global__ __launch_bounds__(256) void s_combine(
    const float* __restrict__ lat, const float* __restrict__ sw,
    const float* __restrict__ fw, const float* __restrict__ fb,
    const int* __restrict__ idx, short* __restrict__ sb)
{
  int n = threadIdx.x & 63;
  int wave = threadIdx.x >> 6;
  int p = blockIdx.x * 4 + wave;         // grid 512 -> p in [0,2048)
  int g = idx[n];
  const float4* fwp = reinterpret_cast<const float4*>(fw + ((size_t)g * 2048 + p) * 1024);
  const float4* swp = reinterpret_cast<const float4*>(sw + (size_t)p * 1024);
  const float4* lp  = reinterpret_cast<const float4*>(lat + (size_t)n * 1024);
  float acc = 0.f;
#pragma unroll 4
  for (int h = 0; h < 256; ++h) {
    float4 lv = lp[h], a = swp[h], b = fwp[h];
    acc = fmaf(lv.x, a.x + b.x, acc);
    acc = fmaf(lv.y, a.y + b.y, acc);
    acc = fmaf(lv.z, a.z + b.z, acc);
    acc = fmaf(lv.w, a.w + b.w, acc);
  }
  sb[(size_t)n * 2048 + p] = f2bf(acc + fb[(size_t)g * 2048 + p]);
}

// part[by][0:64, col] = sb(64x2048 bf16) @ embed_w^T over K-half by.
// LDS-free: B-frags built from direct global f32 loads (in-register f2bf),
// A-frags 16B bf16 loads from L2-resident sb. 4 waves, 32 E-rows/wave (FN=2).
__global__ __launch_bounds__(256) void gemm_embed(
    const short* __restrict__ sb, const float* __restrict__ E,
    float* __restrict__ part, int N)
{
  const int lane = threadIdx.x & 63;
  const int wave = threadIdx.x >> 6;
  const int rl = lane & 15;
  const int lh = lane >> 4;
  const int row0 = blockIdx.x * 128 + wave * 32;   // E-row base for this wave
  const int kbeg = blockIdx.y * 1024;

  f32x4 acc[4][2] = {};
  const int r0 = row0 + rl;
  const int r1 = r0 + 16;
  const bool ok0 = r0 < N, ok1 = r1 < N;
  const float* e0 = E + (size_t)r0 * 2048;
  const float* e1 = E + (size_t)r1 * 2048;
  const short* ap = sb + (size_t)rl * 2048;

#pragma unroll 2
  for (int ks = 0; ks < 32; ++ks) {
    const int k0 = kbeg + ks * 32 + lh * 8;
    bf16x8 b0 = {}, b1 = {};
    if (ok0) {
      float4 u = *reinterpret_cast<const float4*>(e0 + k0);
      float4 v = *reinterpret_cast<const float4*>(e0 + k0 + 4);
      b0[0] = f2bf(u.x); b0[1] = f2bf(u.y); b0[2] = f2bf(u.z); b0[3] = f2bf(u.w);
      b0[4] = f2bf(v.x); b0[5] = f2bf(v.y); b0[6] = f2bf(v.z); b0[7] = f2bf(v.w);
    }
    if (ok1) {
      float4 u = *reinterpret_cast<const float4*>(e1 + k0);
      float4 v = *reinterpret_cast<const float4*>(e1 + k0 + 4);
      b1[0] = f2bf(u.x); b1[1] = f2bf(u.y); b1[2] = f2bf(u.z); b1[3] = f2bf(u.w);
      b1[4] = f2bf(v.x); b1[5] = f2bf(v.y); b1[6] = f2bf(v.z); b1[7] = f2bf(v.w);
    }
    bf16x8 a[4];
#pragma unroll
    for (int mi = 0; mi < 4; ++mi)
      a[mi] = *reinterpret_cast<const bf16x8*>(ap + (size_t)mi * 16 * 2048 + k0);
#pragma unroll
    for (int mi = 0; mi < 4; ++mi) {
      acc[mi][0] = __builtin_amdgcn_mfma_f32_16x16x32_bf16(a[mi], b0, acc[mi][0], 0, 0, 0);
      acc[mi][1] = __builtin_amdgcn_mfma_f32_16x16x32_bf16(a[mi], b1, acc[mi][1], 0, 0, 0);
    }
  }

  // C/D layout: col(lane&15)=E-row frag idx, row=(lane>>4)*4+j = s-row (n)
  float* Cp = part + (size_t)blockIdx.y * 64 * N;
#pragma unroll
  for (int ni = 0; ni < 2; ++ni) {
    int col = row0 + ni * 16 + rl;
    if (col >= N) continue;
#pragma unroll
    for (int mi = 0; mi < 4; ++mi)
#pragma unroll
      for (int j = 0; j < 4; ++j)
        Cp[(size_t)(mi * 16 + lh * 4 + j) * N + col] = acc[mi][ni][j];
  }
}

// out = part[0]+part[1] + 2*embed_b  (float4)
__global__ __launch_bounds__(256) void reduce_out(
    const float* __restrict__ part, const float* __restrict__ eb,
    float* __restrict__ out)
{
  const int NT = 39548;                       // divisible by 4
  const size_t S = (size_t)64 * NT / 4;       // f4 elems per slab
  size_t i = (size_t)blockIdx.x * 256 + threadIdx.x;
  if (i >= S) return;
  const f32x4* p = reinterpret_cast<const f32x4*>(part);
  f32x4 a = p[i] + p[i + S];
  int col = (int)(i % (NT / 4)) * 4;
  f32x4 b = *reinterpret_cast<const f32x4*>(eb + col);
  f32x4 r;
  r[0] = a[0] + 2.f * b[0];
  r[1] = a[1] + 2.f * b[1];
  r[2] = a[2] + 2.f * b[2];
  r[3] = a[3] + 2.f * b[3];
  reinterpret_cast<f32x4*>(out)[i] = r;
}

extern "C" void kernel_launch(void* const* d_in, const int* in_sizes, int n_in,
                              void* d_out, int out_size, void* d_ws, size_t ws_size,
                              hipStream_t stream)
{
  const float* x0       = (const float*)d_in[0];
  const float* x1       = (const float*)d_in[1];
  const float* w1_0     = (const float*)d_in[2];
  const float* w2_0     = (const float*)d_in[3];
  const float* gamma0   = (const float*)d_in[4];
  const float* beta0    = (const float*)d_in[5];
  const float* w1_1     = (const float*)d_in[6];
  const float* w2_1     = (const float*)d_in[7];
  const float* gamma1   = (const float*)d_in[8];
  const float* beta1    = (const float*)d_in[9];
  const float* shared_w = (const float*)d_in[10];
  const float* fc_w     = (const float*)d_in[11];
  const float* fc_b     = (const float*)d_in[12];
  const float* embed_w  = (const float*)d_in[13];
  const float* embed_b  = (const float*)d_in[14];
  const int*   indices  = (const int*)d_in[15];
  float* out = (float*)d_out;

  // ws layout (bf16 region reused as embed partials later)
  short* x0b  = (short*)d_ws;                       // 16512 x 1024 (64 pad rows)
  short* x1b  = x0b + (size_t)16512 * 1024;         // 12672 x 768  (64 pad rows)
  short* w20b = x1b + (size_t)12672 * 768;          // 1024 x 1024
  short* w21b = w20b + (size_t)1024 * 1024;         // 1024 x 768
  float* z0   = (float*)(w21b + (size_t)1024 * 768);
  float* z1   = z0 + 64 * 1024;
  float* lat  = z1 + 64 * 1024;
  short* sb   = (short*)(lat + 64 * 1024);          // 64 x 2048 bf16
  float* part = (float*)d_ws;                       // 2 x 64 x 39548 f32 = 20.2MB, aliases x0b

  // zero z0,z1 (contiguous) for the fused-reduce atomics
  hipMemsetAsync(z0, 0, 2 * 64 * 1024 * sizeof(float), stream);

  // bf16 pre-pass
  to_bf16<<<8224, 256, 0, stream>>>(x0, x0b, 16448 * 1024 / 8);
  hipMemsetAsync(x0b + (size_t)16448 * 1024, 0, 64 * 1024 * sizeof(short), stream);
  to_bf16<<<4728, 256, 0, stream>>>(x1, x1b, 12608 * 768 / 8);
  hipMemsetAsync(x1b + (size_t)12608 * 768, 0, 64 * 768 * sizeof(short), stream);
  to_bf16<<<512, 256, 0, stream>>>(w2_0, w20b, 1024 * 1024 / 8);
  to_bf16<<<384, 256, 0, stream>>>(w2_1, w21b, 1024 * 768 / 8);

  // feature projections with fused l-reduction
  gemm_fused<257><<<dim3(8, 129), 256, 0, stream>>>(x0b, w20b, w1_0, z0, 16448, 1024);
  gemm_fused<197><<<dim3(8, 99),  256, 0, stream>>>(x1b, w21b, w1_1, z1, 12608, 768);

  // BN + latent (row-major)
  bn_latent<<<4, 256, 0, stream>>>(z0, z1, gamma0, beta0, gamma1, beta1, lat);
  // sb = bf16( latent@(shared_w+fc_w_gathered)^T + fc_b )
  s_combine<<<512, 256, 0, stream>>>(lat, shared_w, fc_w, fc_b, indices, sb);

  // out = sb @ embed_w^T + 2*embed_b; LDS-free stream, K-split x2
  gemm_embed<<<dim3(309, 2), 256, 0, stream>>>(sb, embed_w, part, 39548);
  reduce_out<<<2472, 256, 0, stream>>>(part, embed_b, out);
}

// Round 3
// 408.586 us; speedup vs baseline: 1.0903x; 1.0903x over previous
//
#include <hip/hip_runtime.h>
#include <hip/hip_bf16.h>

// GroupLinearEncoder: N=64, L0=257,C0=1024, L1=197,C1=768, H=1024, P=2048, G=8, K=39548
// v4 pipeline:
//   pre-pass: x0,x1,w2_0,w2_1 -> bf16 copies in ws
//   gemm_fused<L>: m97-structure bf16 GEMM (global_load_lds w=16, BK=64, XOR-swizzled LDS)
//     with fused reduce epilogue: z[n,k] += sum_l M[n*L+l,k]*w1[k,l] via atomics
//   bn_latent -> lat[n][h] row-major; s_combine float4-vectorized -> sb (bf16, L2-resident)
//   gemm_embed: out = sb @ E^T + 2*eb directly (no partials). E staged as RAW f32 via
//     global_load_lds (coalesced), cvt to bf16 after ds_read; BN=64 -> grid 618;
//     both-sides XOR swizzle; coalesced out writes.

typedef __attribute__((ext_vector_type(4))) float f32x4;
typedef __attribute__((ext_vector_type(8))) short bf16x8;

__device__ __forceinline__ short f2bf(float v) {
  __hip_bfloat16 h = __float2bfloat16(v);
  union { __hip_bfloat16 b; short s; } u; u.b = h; return u.s;
}

__device__ __forceinline__ void gload16(const short* g, short* l) {
  __builtin_amdgcn_global_load_lds(
      (const __attribute__((address_space(1))) void*)g,
      (__attribute__((address_space(3))) void*)l, 16, 0, 0);
}

__device__ __forceinline__ void gload16f(const float* g, float* l) {
  __builtin_amdgcn_global_load_lds(
      (const __attribute__((address_space(1))) void*)g,
      (__attribute__((address_space(3))) void*)l, 16, 0, 0);
}

// f32 -> bf16, 8 elems/thread
__global__ __launch_bounds__(256) void to_bf16(const float* __restrict__ in,
                                               short* __restrict__ out, int n8)
{
  int i = blockIdx.x * 256 + threadIdx.x;
  if (i >= n8) return;
  const float4* p = reinterpret_cast<const float4*>(in) + 2 * (size_t)i;
  float4 a = p[0], b = p[1];
  bf16x8 o;
  o[0] = f2bf(a.x); o[1] = f2bf(a.y); o[2] = f2bf(a.z); o[3] = f2bf(a.w);
  o[4] = f2bf(b.x); o[5] = f2bf(b.y); o[6] = f2bf(b.z); o[7] = f2bf(b.w);
  *reinterpret_cast<bf16x8*>(out + 8 * (size_t)i) = o;
}

// C = A(bf16, Mpad x K) @ B(bf16, 1024 x K)^T, fused with
// z[n,col] += sum_l C[n*L+l, col] * w1[col*L + l]   (atomics; z pre-zeroed)
// 128x128 tile, BK=64, 4 waves (2x2), FM=FN=4.
template<int L>
__global__ __launch_bounds__(256) void gemm_fused(
    const short* __restrict__ Ab, const short* __restrict__ Bb,
    const float* __restrict__ w1, float* __restrict__ z,
    int M, int K)
{
  __shared__ short As[128 * 64];
  __shared__ short Bs[128 * 64];
  const int tid  = threadIdx.x;
  const int lane = tid & 63;
  const int wave = tid >> 6;
  const int wm = wave >> 1, wn = wave & 1;
  const int tile_m = blockIdx.y * 128;
  const int tile_n = blockIdx.x * 128;
  const int rl = lane & 15;
  const int lh = lane >> 4;

  f32x4 acc[4][4] = {};

  for (int k0 = 0; k0 < K; k0 += 64) {
    __syncthreads();
#pragma unroll
    for (int c = 0; c < 4; ++c) {
      int o = (c * 256 + tid) * 16;
      int r = o >> 7;
      int sc = ((o >> 4) & 7) ^ (r & 7);
      gload16(Ab + (size_t)(tile_m + r) * K + k0 + sc * 8,
              (short*)((char*)As + o));
    }
#pragma unroll
    for (int c = 0; c < 4; ++c) {
      int o = (c * 256 + tid) * 16;
      int r = o >> 7;
      int sc = ((o >> 4) & 7) ^ (r & 7);
      gload16(Bb + (size_t)(tile_n + r) * K + k0 + sc * 8,
              (short*)((char*)Bs + o));
    }
    __syncthreads();

#pragma unroll
    for (int ks = 0; ks < 2; ++ks) {
      bf16x8 af[4], bfr[4];
#pragma unroll
      for (int mi = 0; mi < 4; ++mi) {
        int r = wm * 64 + mi * 16 + rl;
        int j = (ks * 4 + lh) ^ (r & 7);
        af[mi] = *reinterpret_cast<const bf16x8*>((const char*)As + r * 128 + j * 16);
      }
#pragma unroll
      for (int ni = 0; ni < 4; ++ni) {
        int r = wn * 64 + ni * 16 + rl;
        int j = (ks * 4 + lh) ^ (r & 7);
        bfr[ni] = *reinterpret_cast<const bf16x8*>((const char*)Bs + r * 128 + j * 16);
      }
#pragma unroll
      for (int mi = 0; mi < 4; ++mi)
#pragma unroll
        for (int ni = 0; ni < 4; ++ni)
          acc[mi][ni] = __builtin_amdgcn_mfma_f32_16x16x32_bf16(af[mi], bfr[ni], acc[mi][ni], 0, 0, 0);
    }
  }

  // fused reduce_z epilogue. C/D layout: col=lane&15, row=(lane>>4)*4+j (m89).
#pragma unroll
  for (int ni = 0; ni < 4; ++ni) {
    int col = tile_n + wn * 64 + ni * 16 + rl;
    float zac = 0.f;
    int curn = -1;
#pragma unroll
    for (int mi = 0; mi < 4; ++mi) {
#pragma unroll
      for (int j = 0; j < 4; ++j) {
        int row = tile_m + wm * 64 + mi * 16 + lh * 4 + j;
        if (row < M) {
          int n = row / L, l = row - n * L;
          float v = acc[mi][ni][j] * w1[(size_t)col * L + l];
          if (n != curn) {
            if (curn >= 0) atomicAdd(z + curn * 1024 + col, zac);
            curn = n; zac = 0.f;
          }
          zac += v;
        }
      }
    }
    if (curn >= 0) atomicAdd(z + curn * 1024 + col, zac);
  }
}

// BN(z0), BN(z1) (biased stats over n=64), latent=0.5*(...+...), stored lat[n*1024+k]
__global__ void bn_latent(const float* __restrict__ z0, const float* __restrict__ z1,
                          const float* __restrict__ g0, const float* __restrict__ b0,
                          const float* __restrict__ g1, const float* __restrict__ b1,
                          float* __restrict__ lat)
{
  int k = blockIdx.x * blockDim.x + threadIdx.x;
  if (k >= 1024) return;
  float s0 = 0.f, q0 = 0.f, s1 = 0.f, q1 = 0.f;
  for (int n = 0; n < 64; ++n) {
    float v = z0[n * 1024 + k]; s0 += v; q0 += v * v;
    float w = z1[n * 1024 + k]; s1 += w; q1 += w * w;
  }
  float mu0 = s0 * (1.f / 64.f), var0 = q0 * (1.f / 64.f) - mu0 * mu0;
  float mu1 = s1 * (1.f / 64.f), var1 = q1 * (1.f / 64.f) - mu1 * mu1;
  float sc0 = g0[k] * rsqrtf(var0 + 1e-5f);
  float sc1 = g1[k] * rsqrtf(var1 + 1e-5f);
  float be0 = b0[k], be1 = b1[k];
  for (int n = 0; n < 64; ++n) {
    float v = sc0 * (z0[n * 1024 + k] - mu0) + be0
            + sc1 * (z1[n * 1024 + k] - mu1) + be1;
    lat[n * 1024 + k] = 0.5f * v;
  }
}

// sb[n,p] = bf16( lat[n,:]·(sw[p,:]+fw[g_n*2048+p,:]) + fb[g_n*2048+p] )
__global__ __launch_bounds__(256) void s_combine(
    const float* __restrict__ lat, const float* __restrict__ sw,
    const float* __restrict__ fw, const float* __restrict__ fb,
    const int* __restrict__ idx, short* __restrict__ sb)
{
  int n = threadIdx.x & 63;
  int wave = threadIdx.x >> 6;
  int p = blockIdx.x * 4 + wave;         // grid 512 -> p in [0,2048)
  int g = idx[n];
  const float4* fwp = reinterpret_cast<const float4*>(fw + ((size_t)g * 2048 + p) * 1024);
  const float4* swp = reinterpret_cast<const float4*>(sw + (size_t)p * 1024);
  const float4* lp  = reinterpret_cast<const float4*>(lat + (size_t)n * 1024);
  float acc = 0.f;
#pragma unroll 4
  for (int h = 0; h < 256; ++h) {
    float4 lv = lp[h], a = swp[h], b = fwp[h];
    acc = fmaf(lv.x, a.x + b.x, acc);
    acc = fmaf(lv.y, a.y + b.y, acc);
    acc = fmaf(lv.z, a.z + b.z, acc);
    acc = fmaf(lv.w, a.w + b.w, acc);
  }
  sb[(size_t)n * 2048 + p] = f2bf(acc + fb[(size_t)g * 2048 + p]);
}

// out(64 x 39548) = sb(64x2048 bf16) @ E(39548x2048 f32)^T + 2*eb
// BN=64 E-rows per block (grid 618), BK=64, 4 waves each owning 16 E-rows.
// E staged as raw f32 via global_load_lds (coalesced), cvt after ds_read.
// Both-sides XOR swizzle on As (bf16, 8-chunk rows) and Bs (f32, 16-chunk rows).
__global__ __launch_bounds__(256) void gemm_embed(
    const short* __restrict__ sb, const float* __restrict__ E,
    const float* __restrict__ eb, float* __restrict__ out)
{
  __shared__ short As[64 * 64];   // sb tile, 8KB
  __shared__ float Bs[64 * 64];   // E tile, 16KB
  const int tid  = threadIdx.x;
  const int lane = tid & 63;
  const int wave = tid >> 6;
  const int rl = lane & 15;
  const int lh = lane >> 4;
  const int tile_n = blockIdx.x * 64;       // E-row base

  f32x4 acc[4] = {};

  for (int k0 = 0; k0 < 2048; k0 += 64) {
    __syncthreads();
    // stage sb tile (64 x 64 bf16 = 8KB): rows 128B = 8 chunks, swz c^(r&7)
#pragma unroll
    for (int c = 0; c < 2; ++c) {
      int o = (c * 256 + tid) * 16;
      int r = o >> 7;
      int cc = ((o >> 4) & 7) ^ (r & 7);
      gload16(sb + (size_t)r * 2048 + k0 + cc * 8,
              (short*)((char*)As + o));
    }
    // stage E tile (64 x 64 f32 = 16KB): rows 256B = 16 chunks, swz c^(r&15)
#pragma unroll
    for (int c = 0; c < 4; ++c) {
      int o = (c * 256 + tid) * 16;
      int r = o >> 8;
      int cc = ((o >> 4) & 15) ^ (r & 15);
      int gr = tile_n + r; if (gr > 39547) gr = 39547;   // clamp (pad rows dup'd, masked on write)
      gload16f(E + (size_t)gr * 2048 + k0 + cc * 4,
               (float*)((char*)Bs + o));
    }
    __syncthreads();

#pragma unroll
    for (int ks = 0; ks < 2; ++ks) {
      // B frag: E-row br = wave*16+rl, k = ks*32 + lh*8 (f32, 2 chunks) -> cvt bf16
      int br = wave * 16 + rl;
      int c0 = ks * 8 + lh * 2;
      f32x4 u = *reinterpret_cast<const f32x4*>((const char*)Bs + br * 256 + ((c0 ^ (br & 15)) * 16));
      f32x4 v = *reinterpret_cast<const f32x4*>((const char*)Bs + br * 256 + (((c0 + 1) ^ (br & 15)) * 16));
      bf16x8 bf;
      bf[0] = f2bf(u[0]); bf[1] = f2bf(u[1]); bf[2] = f2bf(u[2]); bf[3] = f2bf(u[3]);
      bf[4] = f2bf(v[0]); bf[5] = f2bf(v[1]); bf[6] = f2bf(v[2]); bf[7] = f2bf(v[3]);
#pragma unroll
      for (int mi = 0; mi < 4; ++mi) {
        int ar = mi * 16 + rl;
        int ac = (ks * 4 + lh) ^ (ar & 7);
        bf16x8 af = *reinterpret_cast<const bf16x8*>((const char*)As + ar * 128 + ac * 16);
        acc[mi] = __builtin_amdgcn_mfma_f32_16x16x32_bf16(af, bf, acc[mi], 0, 0, 0);
      }
    }
  }

  // C/D: col(rl) = E-row (this wave's 16), row(lh*4+j) = n (via mi blocks)
  int col = tile_n + wave * 16 + rl;
  if (col < 39548) {
    float bi = 2.f * eb[col];
#pragma unroll
    for (int mi = 0; mi < 4; ++mi)
#pragma unroll
      for (int j = 0; j < 4; ++j) {
        int n = mi * 16 + lh * 4 + j;
        out[(size_t)n * 39548 + col] = acc[mi][j] + bi;
      }
  }
}

extern "C" void kernel_launch(void* const* d_in, const int* in_sizes, int n_in,
                              void* d_out, int out_size, void* d_ws, size_t ws_size,
                              hipStream_t stream)
{
  const float* x0       = (const float*)d_in[0];
  const float* x1       = (const float*)d_in[1];
  const float* w1_0     = (const float*)d_in[2];
  const float* w2_0     = (const float*)d_in[3];
  const float* gamma0   = (const float*)d_in[4];
  const float* beta0    = (const float*)d_in[5];
  const float* w1_1     = (const float*)d_in[6];
  const float* w2_1     = (const float*)d_in[7];
  const float* gamma1   = (const float*)d_in[8];
  const float* beta1    = (const float*)d_in[9];
  const float* shared_w = (const float*)d_in[10];
  const float* fc_w     = (const float*)d_in[11];
  const float* fc_b     = (const float*)d_in[12];
  const float* embed_w  = (const float*)d_in[13];
  const float* embed_b  = (const float*)d_in[14];
  const int*   indices  = (const int*)d_in[15];
  float* out = (float*)d_out;

  // ws layout
  short* x0b  = (short*)d_ws;                       // 16512 x 1024 (64 pad rows)
  short* x1b  = x0b + (size_t)16512 * 1024;         // 12672 x 768  (64 pad rows)
  short* w20b = x1b + (size_t)12672 * 768;          // 1024 x 1024
  short* w21b = w20b + (size_t)1024 * 1024;         // 1024 x 768
  float* z0   = (float*)(w21b + (size_t)1024 * 768);
  float* z1   = z0 + 64 * 1024;
  float* lat  = z1 + 64 * 1024;
  short* sb   = (short*)(lat + 64 * 1024);          // 64 x 2048 bf16

  // zero z0,z1 (contiguous) for the fused-reduce atomics
  hipMemsetAsync(z0, 0, 2 * 64 * 1024 * sizeof(float), stream);

  // bf16 pre-pass
  to_bf16<<<8224, 256, 0, stream>>>(x0, x0b, 16448 * 1024 / 8);
  hipMemsetAsync(x0b + (size_t)16448 * 1024, 0, 64 * 1024 * sizeof(short), stream);
  to_bf16<<<4728, 256, 0, stream>>>(x1, x1b, 12608 * 768 / 8);
  hipMemsetAsync(x1b + (size_t)12608 * 768, 0, 64 * 768 * sizeof(short), stream);
  to_bf16<<<512, 256, 0, stream>>>(w2_0, w20b, 1024 * 1024 / 8);
  to_bf16<<<384, 256, 0, stream>>>(w2_1, w21b, 1024 * 768 / 8);

  // feature projections with fused l-reduction
  gemm_fused<257><<<dim3(8, 129), 256, 0, stream>>>(x0b, w20b, w1_0, z0, 16448, 1024);
  gemm_fused<197><<<dim3(8, 99),  256, 0, stream>>>(x1b, w21b, w1_1, z1, 12608, 768);

  // BN + latent (row-major)
  bn_latent<<<4, 256, 0, stream>>>(z0, z1, gamma0, beta0, gamma1, beta1, lat);
  // sb = bf16( latent@(shared_w+fc_w_gathered)^T + fc_b )
  s_combine<<<512, 256, 0, stream>>>(lat, shared_w, fc_w, fc_b, indices, sb);

  // out = sb @ embed_w^T + 2*embed_b, direct (no partials)
  gemm_embed<<<618, 256, 0, stream>>>(sb, embed_w, embed_b, out);
}

// Round 4
// 394.102 us; speedup vs baseline: 1.1303x; 1.0367x over previous
//
#include <hip/hip_runtime.h>
#include <hip/hip_bf16.h>

// GroupLinearEncoder: N=64, L0=257,C0=1024, L1=197,C1=768, H=1024, P=2048, G=8, K=39548
// v5 pipeline:
//   prep: single kernel -> bf16 copies of x0,x1,w2_0,w2_1 (+pad rows zeroed) + z0/z1 zeroed
//   gemm_fused<L>: m97-structure bf16 GEMM (global_load_lds w=16, BK=64, XOR-swizzled LDS)
//     + XCD-chunked block swizzle; fused reduce epilogue z[n,k] += ... via atomics
//   bn_latent -> lat[n][h]; s_combine float4 -> sb (bf16, L2-resident)
//   gemm_embed: K-split x2 (grid 618x2 = 1236 blocks, 4.8/CU for HBM continuity);
//     E staged as RAW f32 via global_load_lds, cvt after ds_read; both-sides XOR swizzle
//   reduce_out: part0+part1 + 2*embed_b

typedef __attribute__((ext_vector_type(4))) float f32x4;
typedef __attribute__((ext_vector_type(8))) short bf16x8;

__device__ __forceinline__ short f2bf(float v) {
  __hip_bfloat16 h = __float2bfloat16(v);
  union { __hip_bfloat16 b; short s; } u; u.b = h; return u.s;
}

__device__ __forceinline__ void gload16(const short* g, short* l) {
  __builtin_amdgcn_global_load_lds(
      (const __attribute__((address_space(1))) void*)g,
      (__attribute__((address_space(3))) void*)l, 16, 0, 0);
}

__device__ __forceinline__ void gload16f(const float* g, float* l) {
  __builtin_amdgcn_global_load_lds(
      (const __attribute__((address_space(1))) void*)g,
      (__attribute__((address_space(3))) void*)l, 16, 0, 0);
}

__device__ __forceinline__ void cvt8(const float* __restrict__ in,
                                     short* __restrict__ out, size_t i) {
  const float4* p = reinterpret_cast<const float4*>(in) + 2 * i;
  float4 a = p[0], b = p[1];
  bf16x8 o;
  o[0] = f2bf(a.x); o[1] = f2bf(a.y); o[2] = f2bf(a.z); o[3] = f2bf(a.w);
  o[4] = f2bf(b.x); o[5] = f2bf(b.y); o[6] = f2bf(b.z); o[7] = f2bf(b.w);
  *reinterpret_cast<bf16x8*>(out + 8 * i) = o;
}

// One kernel: all f32->bf16 conversions, pad-row zeroing, z0/z1 zeroing.
__global__ __launch_bounds__(256) void prep(
    const float* __restrict__ x0, const float* __restrict__ x1,
    const float* __restrict__ w20, const float* __restrict__ w21,
    short* __restrict__ x0b, short* __restrict__ x1b,
    short* __restrict__ w20b, short* __restrict__ w21b, float* __restrict__ zz)
{
  size_t i = (size_t)blockIdx.x * 256 + threadIdx.x;
  // segment sizes in 8-element units
  const size_t C0 = 2105344;            // x0 cvt  (16448*1024/8)
  const size_t C1 = C0 + 8192;          // x0 pad  (64*1024/8)
  const size_t C2 = C1 + 1210368;       // x1 cvt  (12608*768/8)
  const size_t C3 = C2 + 6144;          // x1 pad  (64*768/8)
  const size_t C4 = C3 + 131072;        // w2_0    (1024*1024/8)
  const size_t C5 = C4 + 98304;         // w2_1    (1024*768/8)
  // C5 + 16384 (z zero) = 3575808 = 256*13968, grid covers exactly
  if (i < C0) { cvt8(x0, x0b, i); return; }
  if (i < C1) {
    bf16x8 zv = {};
    *reinterpret_cast<bf16x8*>(x0b + (size_t)16448 * 1024 + 8 * (i - C0)) = zv;
    return;
  }
  if (i < C2) { cvt8(x1, x1b, i - C1); return; }
  if (i < C3) {
    bf16x8 zv = {};
    *reinterpret_cast<bf16x8*>(x1b + (size_t)12608 * 768 + 8 * (i - C2)) = zv;
    return;
  }
  if (i < C4) { cvt8(w20, w20b, i - C3); return; }
  if (i < C5) { cvt8(w21, w21b, i - C4); return; }
  f32x4 z4 = {};
  f32x4* zp = reinterpret_cast<f32x4*>(zz) + 2 * (i - C5);
  zp[0] = z4; zp[1] = z4;
}

// C = A(bf16, Mpad x K) @ B(bf16, 1024 x K)^T, fused with
// z[n,col] += sum_l C[n*L+l, col] * w1[col*L + l]   (atomics; z pre-zeroed)
// 128x128 tile, BK=64, 4 waves (2x2), FM=FN=4. XCD-chunked block swizzle.
template<int L>
__global__ __launch_bounds__(256) void gemm_fused(
    const short* __restrict__ Ab, const short* __restrict__ Bb,
    const float* __restrict__ w1, float* __restrict__ z,
    int M, int K)
{
  __shared__ short As[128 * 64];
  __shared__ short Bs[128 * 64];
  const int tid  = threadIdx.x;
  const int lane = tid & 63;
  const int wave = tid >> 6;
  const int wm = wave >> 1, wn = wave & 1;

  // XCD-chunked swizzle: nwg divisible by 8 (1032 / 792). Each XCD gets a
  // contiguous orig-range -> w2b tile stays L2-resident, A panels local.
  const int hw  = blockIdx.y * gridDim.x + blockIdx.x;
  const int cpx = (gridDim.x * gridDim.y) >> 3;
  const int orig = (hw & 7) * cpx + (hw >> 3);
  const int tile_m = (orig >> 3) * 128;   // gridDim.x == 8
  const int tile_n = (orig & 7) * 128;

  const int rl = lane & 15;
  const int lh = lane >> 4;

  f32x4 acc[4][4] = {};

  for (int k0 = 0; k0 < K; k0 += 64) {
    __syncthreads();
#pragma unroll
    for (int c = 0; c < 4; ++c) {
      int o = (c * 256 + tid) * 16;
      int r = o >> 7;
      int sc = ((o >> 4) & 7) ^ (r & 7);
      gload16(Ab + (size_t)(tile_m + r) * K + k0 + sc * 8,
              (short*)((char*)As + o));
    }
#pragma unroll
    for (int c = 0; c < 4; ++c) {
      int o = (c * 256 + tid) * 16;
      int r = o >> 7;
      int sc = ((o >> 4) & 7) ^ (r & 7);
      gload16(Bb + (size_t)(tile_n + r) * K + k0 + sc * 8,
              (short*)((char*)Bs + o));
    }
    __syncthreads();

#pragma unroll
    for (int ks = 0; ks < 2; ++ks) {
      bf16x8 af[4], bfr[4];
#pragma unroll
      for (int mi = 0; mi < 4; ++mi) {
        int r = wm * 64 + mi * 16 + rl;
        int j = (ks * 4 + lh) ^ (r & 7);
        af[mi] = *reinterpret_cast<const bf16x8*>((const char*)As + r * 128 + j * 16);
      }
#pragma unroll
      for (int ni = 0; ni < 4; ++ni) {
        int r = wn * 64 + ni * 16 + rl;
        int j = (ks * 4 + lh) ^ (r & 7);
        bfr[ni] = *reinterpret_cast<const bf16x8*>((const char*)Bs + r * 128 + j * 16);
      }
#pragma unroll
      for (int mi = 0; mi < 4; ++mi)
#pragma unroll
        for (int ni = 0; ni < 4; ++ni)
          acc[mi][ni] = __builtin_amdgcn_mfma_f32_16x16x32_bf16(af[mi], bfr[ni], acc[mi][ni], 0, 0, 0);
    }
  }

  // fused reduce_z epilogue. C/D layout: col=lane&15, row=(lane>>4)*4+j (m89).
#pragma unroll
  for (int ni = 0; ni < 4; ++ni) {
    int col = tile_n + wn * 64 + ni * 16 + rl;
    float zac = 0.f;
    int curn = -1;
#pragma unroll
    for (int mi = 0; mi < 4; ++mi) {
#pragma unroll
      for (int j = 0; j < 4; ++j) {
        int row = tile_m + wm * 64 + mi * 16 + lh * 4 + j;
        if (row < M) {
          int n = row / L, l = row - n * L;
          float v = acc[mi][ni][j] * w1[(size_t)col * L + l];
          if (n != curn) {
            if (curn >= 0) atomicAdd(z + curn * 1024 + col, zac);
            curn = n; zac = 0.f;
          }
          zac += v;
        }
      }
    }
    if (curn >= 0) atomicAdd(z + curn * 1024 + col, zac);
  }
}

// BN(z0), BN(z1) (biased stats over n=64), latent=0.5*(...+...), stored lat[n*1024+k]
__global__ void bn_latent(const float* __restrict__ z0, const float* __restrict__ z1,
                          const float* __restrict__ g0, const float* __restrict__ b0,
                          const float* __restrict__ g1, const float* __restrict__ b1,
                          float* __restrict__ lat)
{
  int k = blockIdx.x * blockDim.x + threadIdx.x;
  if (k >= 1024) return;
  float s0 = 0.f, q0 = 0.f, s1 = 0.f, q1 = 0.f;
  for (int n = 0; n < 64; ++n) {
    float v = z0[n * 1024 + k]; s0 += v; q0 += v * v;
    float w = z1[n * 1024 + k]; s1 += w; q1 += w * w;
  }
  float mu0 = s0 * (1.f / 64.f), var0 = q0 * (1.f / 64.f) - mu0 * mu0;
  float mu1 = s1 * (1.f / 64.f), var1 = q1 * (1.f / 64.f) - mu1 * mu1;
  float sc0 = g0[k] * rsqrtf(var0 + 1e-5f);
  float sc1 = g1[k] * rsqrtf(var1 + 1e-5f);
  float be0 = b0[k], be1 = b1[k];
  for (int n = 0; n < 64; ++n) {
    float v = sc0 * (z0[n * 1024 + k] - mu0) + be0
            + sc1 * (z1[n * 1024 + k] - mu1) + be1;
    lat[n * 1024 + k] = 0.5f * v;
  }
}

// sb[n,p] = bf16( lat[n,:]·(sw[p,:]+fw[g_n*2048+p,:]) + fb[g_n*2048+p] )
__global__ __launch_bounds__(256) void s_combine(
    const float* __restrict__ lat, const float* __restrict__ sw,
    const float* __restrict__ fw, const float* __restrict__ fb,
    const int* __restrict__ idx, short* __restrict__ sb)
{
  int n = threadIdx.x & 63;
  int wave = threadIdx.x >> 6;
  int p = blockIdx.x * 4 + wave;         // grid 512 -> p in [0,2048)
  int g = idx[n];
  const float4* fwp = reinterpret_cast<const float4*>(fw + ((size_t)g * 2048 + p) * 1024);
  const float4* swp = reinterpret_cast<const float4*>(sw + (size_t)p * 1024);
  const float4* lp  = reinterpret_cast<const float4*>(lat + (size_t)n * 1024);
  float acc = 0.f;
#pragma unroll 4
  for (int h = 0; h < 256; ++h) {
    float4 lv = lp[h], a = swp[h], b = fwp[h];
    acc = fmaf(lv.x, a.x + b.x, acc);
    acc = fmaf(lv.y, a.y + b.y, acc);
    acc = fmaf(lv.z, a.z + b.z, acc);
    acc = fmaf(lv.w, a.w + b.w, acc);
  }
  sb[(size_t)n * 2048 + p] = f2bf(acc + fb[(size_t)g * 2048 + p]);
}

// part[by][n, col] = sb(64x2048 bf16) @ E(39548x2048 f32)^T over K-half by.
// BN=64 E-rows, BK=64, grid (618,2) = 1236 blocks (~4.8/CU for HBM continuity).
// E staged raw f32 via global_load_lds (coalesced), cvt after ds_read.
__global__ __launch_bounds__(256) void gemm_embed(
    const short* __restrict__ sb, const float* __restrict__ E,
    float* __restrict__ part)
{
  __shared__ short As[64 * 64];   // sb tile, 8KB
  __shared__ float Bs[64 * 64];   // E tile, 16KB
  const int tid  = threadIdx.x;
  const int lane = tid & 63;
  const int wave = tid >> 6;
  const int rl = lane & 15;
  const int lh = lane >> 4;
  const int tile_n = blockIdx.x * 64;       // E-row base
  const int kbeg = blockIdx.y * 1024;       // K-half

  f32x4 acc[4] = {};

  for (int k0 = kbeg; k0 < kbeg + 1024; k0 += 64) {
    __syncthreads();
    // stage sb tile (64 x 64 bf16 = 8KB): rows 128B = 8 chunks, swz c^(r&7)
#pragma unroll
    for (int c = 0; c < 2; ++c) {
      int o = (c * 256 + tid) * 16;
      int r = o >> 7;
      int cc = ((o >> 4) & 7) ^ (r & 7);
      gload16(sb + (size_t)r * 2048 + k0 + cc * 8,
              (short*)((char*)As + o));
    }
    // stage E tile (64 x 64 f32 = 16KB): rows 256B = 16 chunks, swz c^(r&15)
#pragma unroll
    for (int c = 0; c < 4; ++c) {
      int o = (c * 256 + tid) * 16;
      int r = o >> 8;
      int cc = ((o >> 4) & 15) ^ (r & 15);
      int gr = tile_n + r; if (gr > 39547) gr = 39547;   // clamp (masked on write)
      gload16f(E + (size_t)gr * 2048 + k0 + cc * 4,
               (float*)((char*)Bs + o));
    }
    __syncthreads();

#pragma unroll
    for (int ks = 0; ks < 2; ++ks) {
      int br = wave * 16 + rl;
      int c0 = ks * 8 + lh * 2;
      f32x4 u = *reinterpret_cast<const f32x4*>((const char*)Bs + br * 256 + ((c0 ^ (br & 15)) * 16));
      f32x4 v = *reinterpret_cast<const f32x4*>((const char*)Bs + br * 256 + (((c0 + 1) ^ (br & 15)) * 16));
      bf16x8 bf;
      bf[0] = f2bf(u[0]); bf[1] = f2bf(u[1]); bf[2] = f2bf(u[2]); bf[3] = f2bf(u[3]);
      bf[4] = f2bf(v[0]); bf[5] = f2bf(v[1]); bf[6] = f2bf(v[2]); bf[7] = f2bf(v[3]);
#pragma unroll
      for (int mi = 0; mi < 4; ++mi) {
        int ar = mi * 16 + rl;
        int ac = (ks * 4 + lh) ^ (ar & 7);
        bf16x8 af = *reinterpret_cast<const bf16x8*>((const char*)As + ar * 128 + ac * 16);
        acc[mi] = __builtin_amdgcn_mfma_f32_16x16x32_bf16(af, bf, acc[mi], 0, 0, 0);
      }
    }
  }

  // C/D: col(rl) = E-row (this wave's 16), row(lh*4+j) = n (via mi blocks)
  int col = tile_n + wave * 16 + rl;
  if (col < 39548) {
    float* Cp = part + (size_t)blockIdx.y * 64 * 39548;
#pragma unroll
    for (int mi = 0; mi < 4; ++mi)
#pragma unroll
      for (int j = 0; j < 4; ++j) {
        int n = mi * 16 + lh * 4 + j;
        Cp[(size_t)n * 39548 + col] = acc[mi][j];
      }
  }
}

// out = part[0]+part[1] + 2*embed_b  (float4)
__global__ __launch_bounds__(256) void reduce_out(
    const float* __restrict__ part, const float* __restrict__ eb,
    float* __restrict__ out)
{
  const int NT = 39548;                       // divisible by 4
  const size_t S = (size_t)64 * NT / 4;       // f4 elems per slab
  size_t i = (size_t)blockIdx.x * 256 + threadIdx.x;
  if (i >= S) return;
  const f32x4* p = reinterpret_cast<const f32x4*>(part);
  f32x4 a = p[i] + p[i + S];
  int col = (int)(i % (NT / 4)) * 4;
  f32x4 b = *reinterpret_cast<const f32x4*>(eb + col);
  f32x4 r;
  r[0] = a[0] + 2.f * b[0];
  r[1] = a[1] + 2.f * b[1];
  r[2] = a[2] + 2.f * b[2];
  r[3] = a[3] + 2.f * b[3];
  reinterpret_cast<f32x4*>(out)[i] = r;
}

extern "C" void kernel_launch(void* const* d_in, const int* in_sizes, int n_in,
                              void* d_out, int out_size, void* d_ws, size_t ws_size,
                              hipStream_t stream)
{
  const float* x0       = (const float*)d_in[0];
  const float* x1       = (const float*)d_in[1];
  const float* w1_0     = (const float*)d_in[2];
  const float* w2_0     = (const float*)d_in[3];
  const float* gamma0   = (const float*)d_in[4];
  const float* beta0    = (const float*)d_in[5];
  const float* w1_1     = (const float*)d_in[6];
  const float* w2_1     = (const float*)d_in[7];
  const float* gamma1   = (const float*)d_in[8];
  const float* beta1    = (const float*)d_in[9];
  const float* shared_w = (const float*)d_in[10];
  const float* fc_w     = (const float*)d_in[11];
  const float* fc_b     = (const float*)d_in[12];
  const float* embed_w  = (const float*)d_in[13];
  const float* embed_b  = (const float*)d_in[14];
  const int*   indices  = (const int*)d_in[15];
  float* out = (float*)d_out;

  // ws layout
  short* x0b  = (short*)d_ws;                       // 16512 x 1024 (64 pad rows)
  short* x1b  = x0b + (size_t)16512 * 1024;         // 12672 x 768  (64 pad rows)
  short* w20b = x1b + (size_t)12672 * 768;          // 1024 x 1024
  short* w21b = w20b + (size_t)1024 * 1024;         // 1024 x 768
  float* z0   = (float*)(w21b + (size_t)1024 * 768);
  float* z1   = z0 + 64 * 1024;
  float* lat  = z1 + 64 * 1024;
  short* sb   = (short*)(lat + 64 * 1024);          // 64 x 2048 bf16
  float* part = (float*)d_ws;                       // 2 x 64 x 39548 f32 = 20.2MB, aliases x0b

  // all conversions + pad/z zeroing in one launch
  prep<<<13968, 256, 0, stream>>>(x0, x1, w2_0, w2_1, x0b, x1b, w20b, w21b, z0);

  // feature projections with fused l-reduction
  gemm_fused<257><<<dim3(8, 129), 256, 0, stream>>>(x0b, w20b, w1_0, z0, 16448, 1024);
  gemm_fused<197><<<dim3(8, 99),  256, 0, stream>>>(x1b, w21b, w1_1, z1, 12608, 768);

  // BN + latent (row-major)
  bn_latent<<<4, 256, 0, stream>>>(z0, z1, gamma0, beta0, gamma1, beta1, lat);
  // sb = bf16( latent@(shared_w+fc_w_gathered)^T + fc_b )
  s_combine<<<512, 256, 0, stream>>>(lat, shared_w, fc_w, fc_b, indices, sb);

  // out = sb @ embed_w^T + 2*embed_b, K-split x2 for HBM continuity
  gemm_embed<<<dim3(618, 2), 256, 0, stream>>>(sb, embed_w, part);
  reduce_out<<<2472, 256, 0, stream>>>(part, embed_b, out);
}

// Round 5
// 372.080 us; speedup vs baseline: 1.1972x; 1.0592x over previous
//
#include <hip/hip_runtime.h>
#include <hip/hip_bf16.h>

// GroupLinearEncoder: N=64, L0=257,C0=1024, L1=197,C1=768, H=1024, P=2048, G=8, K=39548
// v6 pipeline:
//   prep: bf16 copies of x0,x1,w2_0,w2_1 (+pad rows) + z0/z1 zeroed (one kernel)
//   gemm_fused_dual: BOTH feature-projection GEMMs in one 1824-block launch.
//     min-2-phase double-buffered LDS (BK=32, stage t+1 before compute t, one barrier/step),
//     XCD-chunked block swizzle, fused l-reduce epilogue via atomics.
//   bn_latent -> lat[n][h]; s_combine float4 -> sb (bf16, L2-resident)
//   gemm_embed: dbuf min-2-phase, grid 618 (one generation, 3 blocks/CU), E staged raw f32
//     via global_load_lds, cvt after ds_read, direct out write + 2*embed_b (no partials)

typedef __attribute__((ext_vector_type(4))) float f32x4;
typedef __attribute__((ext_vector_type(8))) short bf16x8;

__device__ __forceinline__ short f2bf(float v) {
  __hip_bfloat16 h = __float2bfloat16(v);
  union { __hip_bfloat16 b; short s; } u; u.b = h; return u.s;
}

__device__ __forceinline__ void gload16(const short* g, short* l) {
  __builtin_amdgcn_global_load_lds(
      (const __attribute__((address_space(1))) void*)g,
      (__attribute__((address_space(3))) void*)l, 16, 0, 0);
}

__device__ __forceinline__ void gload16f(const float* g, float* l) {
  __builtin_amdgcn_global_load_lds(
      (const __attribute__((address_space(1))) void*)g,
      (__attribute__((address_space(3))) void*)l, 16, 0, 0);
}

__device__ __forceinline__ void cvt8(const float* __restrict__ in,
                                     short* __restrict__ out, size_t i) {
  const float4* p = reinterpret_cast<const float4*>(in) + 2 * i;
  float4 a = p[0], b = p[1];
  bf16x8 o;
  o[0] = f2bf(a.x); o[1] = f2bf(a.y); o[2] = f2bf(a.z); o[3] = f2bf(a.w);
  o[4] = f2bf(b.x); o[5] = f2bf(b.y); o[6] = f2bf(b.z); o[7] = f2bf(b.w);
  *reinterpret_cast<bf16x8*>(out + 8 * i) = o;
}

// One kernel: all f32->bf16 conversions, pad-row zeroing, z0/z1 zeroing.
__global__ __launch_bounds__(256) void prep(
    const float* __restrict__ x0, const float* __restrict__ x1,
    const float* __restrict__ w20, const float* __restrict__ w21,
    short* __restrict__ x0b, short* __restrict__ x1b,
    short* __restrict__ w20b, short* __restrict__ w21b, float* __restrict__ zz)
{
  size_t i = (size_t)blockIdx.x * 256 + threadIdx.x;
  const size_t C0 = 2105344;            // x0 cvt  (16448*1024/8)
  const size_t C1 = C0 + 8192;          // x0 pad
  const size_t C2 = C1 + 1210368;       // x1 cvt  (12608*768/8)
  const size_t C3 = C2 + 6144;          // x1 pad
  const size_t C4 = C3 + 131072;        // w2_0
  const size_t C5 = C4 + 98304;         // w2_1
  // C5 + 16384 (z zero) = 3575808 = 256*13968
  if (i < C0) { cvt8(x0, x0b, i); return; }
  if (i < C1) {
    bf16x8 zv = {};
    *reinterpret_cast<bf16x8*>(x0b + (size_t)16448 * 1024 + 8 * (i - C0)) = zv;
    return;
  }
  if (i < C2) { cvt8(x1, x1b, i - C1); return; }
  if (i < C3) {
    bf16x8 zv = {};
    *reinterpret_cast<bf16x8*>(x1b + (size_t)12608 * 768 + 8 * (i - C2)) = zv;
    return;
  }
  if (i < C4) { cvt8(w20, w20b, i - C3); return; }
  if (i < C5) { cvt8(w21, w21b, i - C4); return; }
  f32x4 z4 = {};
  f32x4* zp = reinterpret_cast<f32x4*>(zz) + 2 * (i - C5);
  zp[0] = z4; zp[1] = z4;
}

// ---- fused feature-projection GEMM body (min-2-phase dbuf, BK=32) ----
// C = A(bf16, Mpad x K) @ B(bf16, 1024 x K)^T, fused epilogue:
// z[n,col] += sum_l C[n*L+l, col] * w1[col*L + l]   (atomics; z pre-zeroed)
// 128x128 tile, 4 waves (2x2). LDS chunk swizzle ^((r>>1)&3) keeps both the
// stage (64B/4-lane segments) and the frag ds_reads 2-way (free).
template<int L>
__device__ __forceinline__ void fused_body(
    const short* __restrict__ Ab, const short* __restrict__ Bb,
    const float* __restrict__ w1, float* __restrict__ z,
    int M, int K, int orig, short* As, short* Bs, int tid)
{
  const int lane = tid & 63;
  const int wave = tid >> 6;
  const int wm = wave >> 1, wn = wave & 1;
  const int tile_m = (orig >> 3) * 128;
  const int tile_n = (orig & 7) * 128;
  const int rl = lane & 15;
  const int lh = lane >> 4;

  f32x4 acc[4][4] = {};
  const int nt = K >> 5;

  auto stage = [&](short* dstA, short* dstB, int k0) {
#pragma unroll
    for (int c = 0; c < 2; ++c) {
      int o = (c * 256 + tid) * 16;
      int r = o >> 6;
      int sc = ((o >> 4) & 3) ^ ((r >> 1) & 3);
      gload16(Ab + (size_t)(tile_m + r) * K + k0 + sc * 8, (short*)((char*)dstA + o));
    }
#pragma unroll
    for (int c = 0; c < 2; ++c) {
      int o = (c * 256 + tid) * 16;
      int r = o >> 6;
      int sc = ((o >> 4) & 3) ^ ((r >> 1) & 3);
      gload16(Bb + (size_t)(tile_n + r) * K + k0 + sc * 8, (short*)((char*)dstB + o));
    }
  };

  stage(As, Bs, 0);
  __syncthreads();
  int cur = 0;
  for (int t = 0; t < nt; ++t) {
    if (t + 1 < nt)
      stage(As + (cur ^ 1) * 4096, Bs + (cur ^ 1) * 4096, (t + 1) * 32);
    const char* pa = (const char*)(As + cur * 4096);
    const char* pb = (const char*)(Bs + cur * 4096);
    bf16x8 af[4], bfr[4];
#pragma unroll
    for (int mi = 0; mi < 4; ++mi) {
      int r = wm * 64 + mi * 16 + rl;
      int j = lh ^ ((r >> 1) & 3);
      af[mi] = *reinterpret_cast<const bf16x8*>(pa + r * 64 + j * 16);
    }
#pragma unroll
    for (int ni = 0; ni < 4; ++ni) {
      int r = wn * 64 + ni * 16 + rl;
      int j = lh ^ ((r >> 1) & 3);
      bfr[ni] = *reinterpret_cast<const bf16x8*>(pb + r * 64 + j * 16);
    }
#pragma unroll
    for (int mi = 0; mi < 4; ++mi)
#pragma unroll
      for (int ni = 0; ni < 4; ++ni)
        acc[mi][ni] = __builtin_amdgcn_mfma_f32_16x16x32_bf16(af[mi], bfr[ni], acc[mi][ni], 0, 0, 0);
    __syncthreads();   // drains the t+1 stage (issued before compute -> latency hidden)
    cur ^= 1;
  }

  // fused reduce_z epilogue. C/D layout: col=lane&15, row=(lane>>4)*4+j (m89).
#pragma unroll
  for (int ni = 0; ni < 4; ++ni) {
    int col = tile_n + wn * 64 + ni * 16 + rl;
    float zac = 0.f;
    int curn = -1;
#pragma unroll
    for (int mi = 0; mi < 4; ++mi) {
#pragma unroll
      for (int j = 0; j < 4; ++j) {
        int row = tile_m + wm * 64 + mi * 16 + lh * 4 + j;
        if (row < M) {
          int n = row / L, l = row - n * L;
          float v = acc[mi][ni][j] * w1[(size_t)col * L + l];
          if (n != curn) {
            if (curn >= 0) atomicAdd(z + curn * 1024 + col, zac);
            curn = n; zac = 0.f;
          }
          zac += v;
        }
      }
    }
    if (curn >= 0) atomicAdd(z + curn * 1024 + col, zac);
  }
}

// Both feature-projection GEMMs in one launch: blocks [0,1032) -> path0, [1032,1824) -> path1.
// Per-half XCD-chunked swizzle (both halves' sizes divisible by 8, offset 1032 % 8 == 0).
__global__ __launch_bounds__(256) void gemm_fused_dual(
    const short* __restrict__ x0b, const short* __restrict__ w20b,
    const float* __restrict__ w1_0, float* __restrict__ z0,
    const short* __restrict__ x1b, const short* __restrict__ w21b,
    const float* __restrict__ w1_1, float* __restrict__ z1)
{
  __shared__ short As[2 * 128 * 32];
  __shared__ short Bs[2 * 128 * 32];
  const int flat = blockIdx.x;
  const int tid = threadIdx.x;
  if (flat < 1032) {
    const int cpx = 1032 / 8;
    const int orig = (flat & 7) * cpx + (flat >> 3);
    fused_body<257>(x0b, w20b, w1_0, z0, 16448, 1024, orig, As, Bs, tid);
  } else {
    const int f = flat - 1032;
    const int cpx = 792 / 8;
    const int orig = (f & 7) * cpx + (f >> 3);
    fused_body<197>(x1b, w21b, w1_1, z1, 12608, 768, orig, As, Bs, tid);
  }
}

// BN(z0), BN(z1) (biased stats over n=64), latent=0.5*(...+...), stored lat[n*1024+k]
__global__ void bn_latent(const float* __restrict__ z0, const float* __restrict__ z1,
                          const float* __restrict__ g0, const float* __restrict__ b0,
                          const float* __restrict__ g1, const float* __restrict__ b1,
                          float* __restrict__ lat)
{
  int k = blockIdx.x * blockDim.x + threadIdx.x;
  if (k >= 1024) return;
  float s0 = 0.f, q0 = 0.f, s1 = 0.f, q1 = 0.f;
  for (int n = 0; n < 64; ++n) {
    float v = z0[n * 1024 + k]; s0 += v; q0 += v * v;
    float w = z1[n * 1024 + k]; s1 += w; q1 += w * w;
  }
  float mu0 = s0 * (1.f / 64.f), var0 = q0 * (1.f / 64.f) - mu0 * mu0;
  float mu1 = s1 * (1.f / 64.f), var1 = q1 * (1.f / 64.f) - mu1 * mu1;
  float sc0 = g0[k] * rsqrtf(var0 + 1e-5f);
  float sc1 = g1[k] * rsqrtf(var1 + 1e-5f);
  float be0 = b0[k], be1 = b1[k];
  for (int n = 0; n < 64; ++n) {
    float v = sc0 * (z0[n * 1024 + k] - mu0) + be0
            + sc1 * (z1[n * 1024 + k] - mu1) + be1;
    lat[n * 1024 + k] = 0.5f * v;
  }
}

// sb[n,p] = bf16( lat[n,:]·(sw[p,:]+fw[g_n*2048+p,:]) + fb[g_n*2048+p] )
__global__ __launch_bounds__(256) void s_combine(
    const float* __restrict__ lat, const float* __restrict__ sw,
    const float* __restrict__ fw, const float* __restrict__ fb,
    const int* __restrict__ idx, short* __restrict__ sb)
{
  int n = threadIdx.x & 63;
  int wave = threadIdx.x >> 6;
  int p = blockIdx.x * 4 + wave;         // grid 512 -> p in [0,2048)
  int g = idx[n];
  const float4* fwp = reinterpret_cast<const float4*>(fw + ((size_t)g * 2048 + p) * 1024);
  const float4* swp = reinterpret_cast<const float4*>(sw + (size_t)p * 1024);
  const float4* lp  = reinterpret_cast<const float4*>(lat + (size_t)n * 1024);
  float acc = 0.f;
#pragma unroll 4
  for (int h = 0; h < 256; ++h) {
    float4 lv = lp[h], a = swp[h], b = fwp[h];
    acc = fmaf(lv.x, a.x + b.x, acc);
    acc = fmaf(lv.y, a.y + b.y, acc);
    acc = fmaf(lv.z, a.z + b.z, acc);
    acc = fmaf(lv.w, a.w + b.w, acc);
  }
  sb[(size_t)n * 2048 + p] = f2bf(acc + fb[(size_t)g * 2048 + p]);
}

// out(64 x 39548) = sb(64x2048 bf16) @ E(39548x2048 f32)^T + 2*eb
// BN=64 E-rows per block (grid 618, one generation at 3 blocks/CU), BK=64,
// min-2-phase dbuf: stage t+1 before computing t. E staged raw f32 via
// global_load_lds (coalesced), cvt after ds_read. Direct out write.
__global__ __launch_bounds__(256) void gemm_embed(
    const short* __restrict__ sb, const float* __restrict__ E,
    const float* __restrict__ eb, float* __restrict__ out)
{
  __shared__ short As[2 * 64 * 64];   // sb tiles, 16KB
  __shared__ float Bs[2 * 64 * 64];   // E tiles, 32KB
  const int tid  = threadIdx.x;
  const int lane = tid & 63;
  const int wave = tid >> 6;
  const int rl = lane & 15;
  const int lh = lane >> 4;
  const int tile_n = blockIdx.x * 64;       // E-row base

  auto stage = [&](int buf, int k0) {
#pragma unroll
    for (int c = 0; c < 2; ++c) {
      int o = (c * 256 + tid) * 16;
      int r = o >> 7;
      int cc = ((o >> 4) & 7) ^ (r & 7);
      gload16(sb + (size_t)r * 2048 + k0 + cc * 8,
              (short*)((char*)(As + buf * 4096) + o));
    }
#pragma unroll
    for (int c = 0; c < 4; ++c) {
      int o = (c * 256 + tid) * 16;
      int r = o >> 8;
      int cc = ((o >> 4) & 15) ^ (r & 15);
      int gr = tile_n + r; if (gr > 39547) gr = 39547;   // clamp (masked on write)
      gload16f(E + (size_t)gr * 2048 + k0 + cc * 4,
               (float*)((char*)(Bs + buf * 4096) + o));
    }
  };

  f32x4 acc[4] = {};
  stage(0, 0);
  __syncthreads();
  int cur = 0;
  for (int t = 0; t < 32; ++t) {
    if (t < 31) stage(cur ^ 1, (t + 1) * 64);
    const char* pa = (const char*)(As + cur * 4096);
    const char* pb = (const char*)(Bs + cur * 4096);
#pragma unroll
    for (int ks = 0; ks < 2; ++ks) {
      int br = wave * 16 + rl;
      int c0 = ks * 8 + lh * 2;
      f32x4 u = *reinterpret_cast<const f32x4*>(pb + br * 256 + ((c0 ^ (br & 15)) * 16));
      f32x4 v = *reinterpret_cast<const f32x4*>(pb + br * 256 + (((c0 + 1) ^ (br & 15)) * 16));
      bf16x8 bf;
      bf[0] = f2bf(u[0]); bf[1] = f2bf(u[1]); bf[2] = f2bf(u[2]); bf[3] = f2bf(u[3]);
      bf[4] = f2bf(v[0]); bf[5] = f2bf(v[1]); bf[6] = f2bf(v[2]); bf[7] = f2bf(v[3]);
#pragma unroll
      for (int mi = 0; mi < 4; ++mi) {
        int ar = mi * 16 + rl;
        int ac = (ks * 4 + lh) ^ (ar & 7);
        bf16x8 af = *reinterpret_cast<const bf16x8*>(pa + ar * 128 + ac * 16);
        acc[mi] = __builtin_amdgcn_mfma_f32_16x16x32_bf16(af, bf, acc[mi], 0, 0, 0);
      }
    }
    __syncthreads();
    cur ^= 1;
  }

  // C/D: col(rl) = E-row (this wave's 16), row(lh*4+j) = n (via mi blocks)
  int col = tile_n + wave * 16 + rl;
  if (col < 39548) {
    float bi = 2.f * eb[col];
#pragma unroll
    for (int mi = 0; mi < 4; ++mi)
#pragma unroll
      for (int j = 0; j < 4; ++j) {
        int n = mi * 16 + lh * 4 + j;
        out[(size_t)n * 39548 + col] = acc[mi][j] + bi;
      }
  }
}

extern "C" void kernel_launch(void* const* d_in, const int* in_sizes, int n_in,
                              void* d_out, int out_size, void* d_ws, size_t ws_size,
                              hipStream_t stream)
{
  const float* x0       = (const float*)d_in[0];
  const float* x1       = (const float*)d_in[1];
  const float* w1_0     = (const float*)d_in[2];
  const float* w2_0     = (const float*)d_in[3];
  const float* gamma0   = (const float*)d_in[4];
  const float* beta0    = (const float*)d_in[5];
  const float* w1_1     = (const float*)d_in[6];
  const float* w2_1     = (const float*)d_in[7];
  const float* gamma1   = (const float*)d_in[8];
  const float* beta1    = (const float*)d_in[9];
  const float* shared_w = (const float*)d_in[10];
  const float* fc_w     = (const float*)d_in[11];
  const float* fc_b     = (const float*)d_in[12];
  const float* embed_w  = (const float*)d_in[13];
  const float* embed_b  = (const float*)d_in[14];
  const int*   indices  = (const int*)d_in[15];
  float* out = (float*)d_out;

  // ws layout
  short* x0b  = (short*)d_ws;                       // 16512 x 1024 (64 pad rows)
  short* x1b  = x0b + (size_t)16512 * 1024;         // 12672 x 768  (64 pad rows)
  short* w20b = x1b + (size_t)12672 * 768;          // 1024 x 1024
  short* w21b = w20b + (size_t)1024 * 1024;         // 1024 x 768
  float* z0   = (float*)(w21b + (size_t)1024 * 768);
  float* z1   = z0 + 64 * 1024;
  float* lat  = z1 + 64 * 1024;
  short* sb   = (short*)(lat + 64 * 1024);          // 64 x 2048 bf16

  // all conversions + pad/z zeroing in one launch
  prep<<<13968, 256, 0, stream>>>(x0, x1, w2_0, w2_1, x0b, x1b, w20b, w21b, z0);

  // both feature projections (fused l-reduction), one launch
  gemm_fused_dual<<<1824, 256, 0, stream>>>(x0b, w20b, w1_0, z0,
                                            x1b, w21b, w1_1, z1);

  // BN + latent (row-major)
  bn_latent<<<16, 64, 0, stream>>>(z0, z1, gamma0, beta0, gamma1, beta1, lat);
  // sb = bf16( latent@(shared_w+fc_w_gathered)^T + fc_b )
  s_combine<<<512, 256, 0, stream>>>(lat, shared_w, fc_w, fc_b, indices, sb);

  // out = sb @ embed_w^T + 2*embed_b, dbuf stream, direct write
  gemm_embed<<<618, 256, 0, stream>>>(sb, embed_w, embed_b, out);
}